// Round 1
// 579.370 us; speedup vs baseline: 1.0985x; 1.0985x over previous
//
#include <hip/hip_runtime.h>
#include <hip/hip_bf16.h>
#include <stdint.h>

// DenseAttention: B=16, S=2048, D=256, fp32 in/out.
// d_out = [output (16*2048*256) | attn_weights (16*2048*2048)] fp32.
// Round plan:
//  - k_attn: SINGLE pass QK^T -> E=exp (unnormalized) written to attn slab,
//    rowsum -> Winv (1/sum) in workspace. q-tile 64, 256 thr, 2 blocks/CU.
//    K tile staged via global_load_lds(16B) with pre-swizzled source addrs.
//  - k_out: reads E, multiplies by Winv, writes NORMALIZED attn back in-place,
//    converts to bf16 for PV MFMA, writes O. Vt staged via global_load_lds.

#define B_ 16
#define S_ 2048
#define D_ 256
#define SCALE_ 0.0625f

typedef __attribute__((ext_vector_type(8))) short bf16x8;
typedef __attribute__((ext_vector_type(4))) float f32x4;

__device__ __forceinline__ uint16_t f2bf(float f) {
  uint32_t u = __float_as_uint(f);
  u += 0x7fffu + ((u >> 16) & 1u);  // RNE
  return (uint16_t)(u >> 16);
}

typedef __attribute__((address_space(3))) uint32_t lds_u32;
typedef __attribute__((address_space(1))) const uint32_t glb_u32;
__device__ __forceinline__ void gload_lds16(const void* g, void* l) {
  // 16B direct global->LDS; LDS dest is wave-uniform base + lane*16.
  __builtin_amdgcn_global_load_lds((glb_u32*)g, (lds_u32*)l, 16, 0, 0);
}

// ---------------- K -> bf16 ----------------
__global__ void k_convert(const float* __restrict__ src, uint16_t* __restrict__ dst) {
  const int t = blockIdx.x * blockDim.x + threadIdx.x;  // 8 elems/thread
  const float4* s = (const float4*)src + (size_t)t * 2;
  float4 a = s[0], b = s[1];
  ushort4 lo = { f2bf(a.x), f2bf(a.y), f2bf(a.z), f2bf(a.w) };
  ushort4 hi = { f2bf(b.x), f2bf(b.y), f2bf(b.z), f2bf(b.w) };
  ((ushort4*)dst)[(size_t)t * 2]     = lo;
  ((ushort4*)dst)[(size_t)t * 2 + 1] = hi;
}

// ---------------- V -> V^T bf16 ----------------
__global__ void k_transpose(const float* __restrict__ V, uint16_t* __restrict__ Vt) {
  __shared__ float tile[64][68];
  const int b = blockIdx.z, kv0 = blockIdx.x * 64, d0 = blockIdx.y * 64;
  const int t = threadIdx.x;
  {
    const int r = t >> 2, c = (t & 3) * 16;
    const float4* src = (const float4*)(V + ((size_t)b * S_ + kv0 + r) * D_ + d0 + c);
    float4 x0 = src[0], x1 = src[1], x2 = src[2], x3 = src[3];
    *(float4*)&tile[r][c]      = x0;
    *(float4*)&tile[r][c + 4]  = x1;
    *(float4*)&tile[r][c + 8]  = x2;
    *(float4*)&tile[r][c + 12] = x3;
  }
  __syncthreads();
  {
    const int dl = t >> 2, c = (t & 3) * 16;
    uint16_t o[16];
#pragma unroll
    for (int i = 0; i < 16; ++i) o[i] = f2bf(tile[c + i][dl]);
    uint16_t* dst = Vt + ((size_t)b * D_ + d0 + dl) * S_ + kv0 + c;
#pragma unroll
    for (int i = 0; i < 4; ++i) {
      ushort4 v4 = { o[4*i], o[4*i+1], o[4*i+2], o[4*i+3] };
      *(ushort4*)(dst + 4*i) = v4;
    }
  }
}

// ---------------- mask -> bit-packed u64 per (row, 64-kv chunk) ----------------
__global__ void k_maskpack(const int* __restrict__ mask, unsigned long long* __restrict__ Mb) {
  const int wid  = blockIdx.x * 4 + (threadIdx.x >> 6);
  const int lane = threadIdx.x & 63;
  const int row = wid >> 5, w64 = wid & 31;
  const int m = mask[(size_t)row * S_ + w64 * 64 + lane];
  unsigned long long bits = __ballot(m != 0);
  if (lane == 0) Mb[row * 32 + w64] = bits;
}

// ---------------- scores, single pass: E = exp(masked s), Winv = 1/rowsum ----
__global__ __launch_bounds__(256, 2) void k_attn(
    const float* __restrict__ Q, const uint16_t* __restrict__ Kb,
    const unsigned long long* __restrict__ Mb,
    float* __restrict__ E, float* __restrict__ Winv) {
  __shared__ uint16_t Ks[128 * 256];  // 64 KB, linear slots; swizzle via source
  const int b = blockIdx.y, q0 = blockIdx.x * 64;
  const int tid = threadIdx.x, w = tid >> 6, lane = tid & 63;
  const int wq = w >> 1, wkv = w & 1;
  const int l15 = lane & 15, lq = lane >> 4;
  const int qbase = q0 + wq * 32;

  // Q fragments in VGPRs: 2 q-subtiles x 8 d-chunks
  bf16x8 aq[2][8];
#pragma unroll
  for (int qt = 0; qt < 2; ++qt) {
    const float* qrow = Q + ((size_t)b * S_ + qbase + qt * 16 + l15) * D_;
#pragma unroll
    for (int dc = 0; dc < 8; ++dc) {
      const float4* p = (const float4*)(qrow + dc * 32 + lq * 8);
      float4 x = p[0], y = p[1];
      union { bf16x8 v; uint16_t u[8]; } fr;
      fr.u[0] = f2bf(x.x); fr.u[1] = f2bf(x.y); fr.u[2] = f2bf(x.z); fr.u[3] = f2bf(x.w);
      fr.u[4] = f2bf(y.x); fr.u[5] = f2bf(y.y); fr.u[6] = f2bf(y.z); fr.u[7] = f2bf(y.w);
      aq[qt][dc] = fr.v;
    }
  }

  float rowpart[2][4] = {{0.f,0.f,0.f,0.f},{0.f,0.f,0.f,0.f}};

  for (int kvt = 0; kvt < 16; ++kvt) {
    const int kvb = kvt * 128;
    __syncthreads();  // Ks free (prev tile's reads done)
    // async stage K tile (128 kv x 256 d bf16) - swizzled SOURCE, linear LDS.
    // LDS slot s (16B granule) holds logical granule g=(c&~7)|((c^r)&7), r=s>>5,c=s&31.
    {
      const uint16_t* tbase = Kb + ((size_t)b * S_ + kvb) * D_;
#pragma unroll
      for (int it = 0; it < 16; ++it) {
        const int s = (it * 4 + w) * 64 + lane;
        const int r = s >> 5, c = s & 31;
        const int g = (c & ~7) | ((c ^ r) & 7);
        gload_lds16(tbase + (size_t)r * D_ + g * 8, &Ks[(it * 4 + w) * 64 * 8]);
      }
    }
    __syncthreads();  // drains vmcnt -> tile ready

    f32x4 acc[2][4];
#pragma unroll
    for (int qt = 0; qt < 2; ++qt)
#pragma unroll
      for (int kt = 0; kt < 4; ++kt) acc[qt][kt] = 0.f;

#pragma unroll
    for (int dc = 0; dc < 8; ++dc) {
      bf16x8 bk[4];
#pragma unroll
      for (int kt = 0; kt < 4; ++kt) {
        const int kvl = wkv * 64 + kt * 16 + l15;
        const int g = dc * 4 + lq;
        const int gs = (g & ~7) | ((g ^ kvl) & 7);
        bk[kt] = *(const bf16x8*)&Ks[(kvl * 32 + gs) * 8];
      }
#pragma unroll
      for (int qt = 0; qt < 2; ++qt)
#pragma unroll
        for (int kt = 0; kt < 4; ++kt)
          acc[qt][kt] = __builtin_amdgcn_mfma_f32_16x16x32_bf16(
              aq[qt][dc], bk[kt], acc[qt][kt], 0, 0, 0);
    }

    // epilogue: exp + mask; store UNNORMALIZED e; accumulate rowsums
#pragma unroll
    for (int qt = 0; qt < 2; ++qt) {
#pragma unroll
      for (int r = 0; r < 4; ++r) {
        const int row = qbase + qt * 16 + lq * 4 + r;
        const unsigned long long mw = Mb[row * 32 + kvt * 2 + wkv];
        float* erow = E + (size_t)b * S_ * S_ + (size_t)row * S_ + kvb + wkv * 64 + l15;
#pragma unroll
        for (int kt = 0; kt < 4; ++kt) {
          const float sc = acc[qt][kt][r] * SCALE_;
          const int bit = kt * 16 + l15;
          const float e = ((mw >> bit) & 1ull) ? __expf(sc) : 0.0f;
          rowpart[qt][r] += e;
          erow[kt * 16] = e;
        }
      }
    }
  }

  // row-sum: reduce 16 lanes sharing a row, then combine wkv halves via LDS
#pragma unroll
  for (int qt = 0; qt < 2; ++qt)
#pragma unroll
    for (int r = 0; r < 4; ++r) {
      float v = rowpart[qt][r];
      v += __shfl_xor(v, 1); v += __shfl_xor(v, 2);
      v += __shfl_xor(v, 4); v += __shfl_xor(v, 8);
      rowpart[qt][r] = v;
    }
  __syncthreads();  // everyone done reading Ks
  float* red = (float*)(void*)Ks;
  if (l15 == 0) {
#pragma unroll
    for (int qt = 0; qt < 2; ++qt)
#pragma unroll
      for (int r = 0; r < 4; ++r) {
        const int rl = wq * 32 + qt * 16 + lq * 4 + r;
        red[wkv * 64 + rl] = rowpart[qt][r];
      }
  }
  __syncthreads();
  if (wkv == 0 && l15 == 0) {
#pragma unroll
    for (int qt = 0; qt < 2; ++qt)
#pragma unroll
      for (int r = 0; r < 4; ++r) {
        const int rl = wq * 32 + qt * 16 + lq * 4 + r;
        Winv[(size_t)b * S_ + q0 + rl] = 1.0f / (red[rl] + red[64 + rl]);
      }
  }
}

// ---------------- O = (E*inv) @ V; also writes normalized attn in-place ------
__global__ __launch_bounds__(256, 2) void k_out(
    float* __restrict__ attn, const uint16_t* __restrict__ Vt,
    const float* __restrict__ Winv, float* __restrict__ O) {
  __shared__ uint16_t As[64 * 64];    // 8 KB swizzled [q][kv]
  __shared__ uint16_t Vs[256 * 64];   // 32 KB swizzled [d][kv], linear-dest gload
  const int b = blockIdx.y, q0 = blockIdx.x * 64;
  const int tid = threadIdx.x, w = tid >> 6, lane = tid & 63;  // w = wd (0..3)
  const int l15 = lane & 15, lq = lane >> 4;
  const int srow = tid >> 2, scol = (tid & 3) * 16;
  const float inv_r = Winv[(size_t)b * S_ + q0 + srow];

  f32x4 acc[4][4];
#pragma unroll
  for (int qt = 0; qt < 4; ++qt)
#pragma unroll
    for (int dt = 0; dt < 4; ++dt) acc[qt][dt] = 0.f;

  for (int kvt = 0; kvt < 32; ++kvt) {
    const int kvb = kvt * 64;
    __syncthreads();  // buffers free
    // Vs: 256 d x 64 kv bf16, swizzled source -> linear LDS.
    // slot s: d=s>>3, c=s&7 holds logical granule g = c ^ (d&7).
    {
      const uint16_t* tbase = Vt + (size_t)b * D_ * S_ + kvb;
#pragma unroll
      for (int it = 0; it < 8; ++it) {
        const int s = (it * 4 + w) * 64 + lane;
        const int d = s >> 3, c = s & 7;
        const int g = c ^ (d & 7);
        gload_lds16(tbase + (size_t)d * S_ + g * 8, &Vs[(it * 4 + w) * 64 * 8]);
      }
    }
    // As: load E tile (64q x 64kv fp32), scale by inv, write back normalized,
    // convert to bf16 into swizzled As.
    {
      float* ap = attn + ((size_t)b * S_ + q0 + srow) * S_ + kvb + scol;
      float4 a0 = ((const float4*)ap)[0], a1 = ((const float4*)ap)[1];
      float4 a2 = ((const float4*)ap)[2], a3 = ((const float4*)ap)[3];
      a0.x *= inv_r; a0.y *= inv_r; a0.z *= inv_r; a0.w *= inv_r;
      a1.x *= inv_r; a1.y *= inv_r; a1.z *= inv_r; a1.w *= inv_r;
      a2.x *= inv_r; a2.y *= inv_r; a2.z *= inv_r; a2.w *= inv_r;
      a3.x *= inv_r; a3.y *= inv_r; a3.z *= inv_r; a3.w *= inv_r;
      ((float4*)ap)[0] = a0; ((float4*)ap)[1] = a1;
      ((float4*)ap)[2] = a2; ((float4*)ap)[3] = a3;
      union { uint4 u; uint16_t h[8]; } g0, g1;
      g0.h[0] = f2bf(a0.x); g0.h[1] = f2bf(a0.y); g0.h[2] = f2bf(a0.z); g0.h[3] = f2bf(a0.w);
      g0.h[4] = f2bf(a1.x); g0.h[5] = f2bf(a1.y); g0.h[6] = f2bf(a1.z); g0.h[7] = f2bf(a1.w);
      g1.h[0] = f2bf(a2.x); g1.h[1] = f2bf(a2.y); g1.h[2] = f2bf(a2.z); g1.h[3] = f2bf(a2.w);
      g1.h[4] = f2bf(a3.x); g1.h[5] = f2bf(a3.y); g1.h[6] = f2bf(a3.z); g1.h[7] = f2bf(a3.w);
      const int gc = (tid & 3) * 2;
      *(uint4*)&As[(srow * 8 + (gc ^ (srow & 7))) * 8]       = g0.u;
      *(uint4*)&As[(srow * 8 + ((gc + 1) ^ (srow & 7))) * 8] = g1.u;
    }
    __syncthreads();

#pragma unroll
    for (int kc = 0; kc < 2; ++kc) {
      bf16x8 af[4], bv[4];
      const int g = kc * 4 + lq;
#pragma unroll
      for (int qt = 0; qt < 4; ++qt) {
        const int ql = qt * 16 + l15;
        af[qt] = *(const bf16x8*)&As[(ql * 8 + (g ^ (ql & 7))) * 8];
      }
#pragma unroll
      for (int dt = 0; dt < 4; ++dt) {
        const int dl = w * 64 + dt * 16 + l15;
        bv[dt] = *(const bf16x8*)&Vs[(dl * 8 + (g ^ (dl & 7))) * 8];
      }
#pragma unroll
      for (int qt = 0; qt < 4; ++qt)
#pragma unroll
        for (int dt = 0; dt < 4; ++dt)
          acc[qt][dt] = __builtin_amdgcn_mfma_f32_16x16x32_bf16(af[qt], bv[dt], acc[qt][dt], 0, 0, 0);
    }
  }

#pragma unroll
  for (int qt = 0; qt < 4; ++qt)
#pragma unroll
    for (int dt = 0; dt < 4; ++dt)
#pragma unroll
      for (int r = 0; r < 4; ++r)
        O[((size_t)b * S_ + q0 + qt * 16 + lq * 4 + r) * D_ +
          w * 64 + dt * 16 + l15] = acc[qt][dt][r];
}

extern "C" void kernel_launch(void* const* d_in, const int* in_sizes, int n_in,
                              void* d_out, int out_size, void* d_ws, size_t ws_size,
                              hipStream_t stream) {
  const float* q = (const float*)d_in[0];
  const float* k = (const float*)d_in[1];
  const float* v = (const float*)d_in[2];
  const int* mask = (const int*)d_in[3];

  float* out  = (float*)d_out;
  float* attn = out + (size_t)B_ * S_ * D_;

  uint16_t* Kb = (uint16_t*)d_ws;                                   // 16.78 MB
  uint16_t* Vt = Kb + (size_t)B_ * S_ * D_;                         // 16.78 MB
  unsigned long long* Mb = (unsigned long long*)(Vt + (size_t)B_ * S_ * D_);  // 0.5 MB
  float* Winv = (float*)(Mb + (size_t)S_ * 32);                     // 128 KB
  // total ws: ~34.2 MB

  k_convert<<<dim3(2048), dim3(512), 0, stream>>>(k, Kb);
  k_transpose<<<dim3(32, 4, 16), dim3(256), 0, stream>>>(v, Vt);
  k_maskpack<<<dim3(16384), dim3(256), 0, stream>>>(mask, Mb);
  k_attn<<<dim3(32, 16), dim3(256), 0, stream>>>(q, Kb, Mb, attn, Winv);
  k_out<<<dim3(32, 16), dim3(256), 0, stream>>>(attn, Vt, Winv, out);
}